// Round 2
// baseline (295.625 us; speedup 1.0000x reference)
//
#include <hip/hip_runtime.h>
#include <hip/hip_bf16.h>

typedef unsigned short u16;
typedef __attribute__((ext_vector_type(4))) unsigned short u16x4;
typedef __attribute__((ext_vector_type(8))) unsigned short u16x8;
typedef __attribute__((ext_vector_type(8))) __bf16 bf16x8;
typedef __attribute__((ext_vector_type(4))) float f32x4;

#define BB 16
#define TSEQ 1024
#define CC 584          /* embed dim */
#define HH 8
#define DHD 73
#define NR (BB*TSEQ)    /* 16384 rows */
#define KPW 640         /* padded K: 10 x 64 -> uniform BK=64 pipeline */
#define KT64 10
#define DP 96           /* padded head dim */
#define HD (HH*DP)      /* 768 */
#define NP3 768         /* padded N for final proj (3 x 256 tiles) */
#define PPITCH 88
/* exp(s*584^-0.5) == exp2(s * CEXP); scores bounded -> no max subtraction */
#define CEXP 0.0596985934f

__device__ __forceinline__ u16 f2bf(float f) {
  __bf16 h = (__bf16)f;                 // native v_cvt, RNE
  return __builtin_bit_cast(u16, h);
}
__device__ __forceinline__ bf16x8 as_bf(u16x8 v) { return __builtin_bit_cast(bf16x8, v); }

/* async global->LDS, 16B/lane, LDS dst = wave-uniform base + lane*16 */
#define GLL16(g, l) __builtin_amdgcn_global_load_lds( \
    (const __attribute__((address_space(1))) void*)(g), \
    (__attribute__((address_space(3))) void*)(l), 16, 0, 0)

#define BARRIER() asm volatile("s_barrier" ::: "memory")
#define VMW8()    asm volatile("s_waitcnt vmcnt(8)" ::: "memory")
#define VMW0()    asm volatile("s_waitcnt vmcnt(0)" ::: "memory")

// ---------------- fused pack kernel ----------------
// phase A (10240 blocks): x|mem [16384,584] f32 -> xmb [32768][640] bf16 zero-padded
// phase B (5760 blocks):  Wq/Wv/Wk -> wt [q 768 | v 768 | k 768 rows][640] bf16
// phase C (1920 blocks):  Wp -> wpt [768][640] bf16 (transposed)
#define PKA 10240
#define PKB 5760
#define PKC 1920
__global__ void pack_all_kernel(const float* __restrict__ x, const float* __restrict__ mem,
                                const float* __restrict__ Wq, const float* __restrict__ Wk,
                                const float* __restrict__ Wv, const float* __restrict__ Wp,
                                u16* __restrict__ xmb, u16* __restrict__ wt,
                                u16* __restrict__ wpt) {
  const int bidx = blockIdx.x;
  const int tid = threadIdx.x;
  if (bidx < PKA) {
    int idx = bidx * 256 + tid;
    int row = idx / (KPW / 8);
    int c8  = (idx % (KPW / 8)) * 8;
    u16x8 o = {0, 0, 0, 0, 0, 0, 0, 0};
    if (c8 < CC) {
      const float* src = (row < NR) ? &x[(size_t)row * CC + c8]
                                    : &mem[(size_t)(row - NR) * CC + c8];
      f32x4 a = *(const f32x4*)src;
      f32x4 b = *(const f32x4*)(src + 4);
#pragma unroll
      for (int t = 0; t < 4; t++) { o[t] = f2bf(a[t]); o[4 + t] = f2bf(b[t]); }
    }
    *(u16x8*)&xmb[(size_t)row * KPW + c8] = o;
  } else if (bidx < PKA + PKB) {
    int idx = (bidx - PKA) * 256 + tid;
    int w   = idx / (HD * KPW);
    int rem = idx % (HD * KPW);
    int n = rem / KPW;
    int k = rem % KPW;
    int h = n / DP, d = n % DP;
    u16 val = 0;
    if (d < DHD && k < CC) {
      const float* W = (w == 0) ? Wq : ((w == 1) ? Wv : Wk);  // order: q, v, k
      val = f2bf(W[((size_t)h * CC + k) * DHD + d]);
    }
    wt[idx] = val;
  } else {
    int idx = (bidx - PKA - PKB) * 256 + tid;
    int n = idx / KPW;
    int c = idx % KPW;
    u16 val = 0;
    if (n < CC && c < CC) val = f2bf(Wp[(size_t)c * CC + n]);
    wpt[idx] = val;
  }
}

// ---------------- 256x256 GEMM, overlapped K-tile schedule ----------------
// C[m][n] = sum_k A[m][k]*Bt[n][k]; 512 threads = 8 waves (2M x 4N), each wave
// owns 128x64 of C. BK=64, LDS = 2buf x (A[256][64] + B[256][64]) bf16 = 128KB.
// Per K-tile t (buf = t&1): issue ALL 24 fragment ds_read_b128 up front (A read
// once, B read once), then 4 MFMA quadrants in dependency order with the
// COMPILER's counted lgkmcnt interleaving reads and MFMA (no manual lgkm drain).
// 2 barriers per K-tile: post-compute (frees buf(t) for staging t+2) and
// post-vmcnt(8) (t+1 staged & visible). vmcnt never drains to 0 mid-loop.
// T2 swizzle: LDS linear, global source column chunk XOR (row&7), ds_read
// applies same XOR (both-sides rule) -> 0 bank conflicts (verified round 1).

template <int MH, int NH>
__device__ __forceinline__ void mm_f(f32x4 (&acc)[8][4], const bf16x8 (&av)[4][2],
                                     const bf16x8 (&bv)[2][2]) {
  __builtin_amdgcn_s_setprio(1);
#pragma unroll
  for (int mq = 0; mq < 4; mq++)
#pragma unroll
    for (int nq = 0; nq < 2; nq++) {
      f32x4 c = acc[MH * 4 + mq][NH * 2 + nq];
      c = __builtin_amdgcn_mfma_f32_16x16x32_bf16(av[mq][0], bv[nq][0], c, 0, 0, 0);
      c = __builtin_amdgcn_mfma_f32_16x16x32_bf16(av[mq][1], bv[nq][1], c, 0, 0, 0);
      acc[MH * 4 + mq][NH * 2 + nq] = c;
    }
  __builtin_amdgcn_s_setprio(0);
}

__device__ __forceinline__ void compute_tile(f32x4 (&acc)[8][4], const u16* lds,
                                             int bufA, int aRow, int bRow,
                                             int sw0, int sw1) {
  const int bufB = bufA + 32768;
  bf16x8 a0[4][2], a1[4][2], b0[2][2], b1[2][2];
  // issue all fragment reads up front; compiler inserts counted lgkmcnt per use
#pragma unroll
  for (int mq = 0; mq < 4; mq++) {
    const int r = bufA + aRow + mq * 1024;
    a0[mq][0] = as_bf(*(const u16x8*)&lds[r + sw0]);
    a0[mq][1] = as_bf(*(const u16x8*)&lds[r + sw1]);
  }
#pragma unroll
  for (int nq = 0; nq < 2; nq++) {
    const int r = bufB + bRow + nq * 1024;
    b0[nq][0] = as_bf(*(const u16x8*)&lds[r + sw0]);
    b0[nq][1] = as_bf(*(const u16x8*)&lds[r + sw1]);
  }
#pragma unroll
  for (int nq = 0; nq < 2; nq++) {
    const int r = bufB + bRow + 2048 + nq * 1024;
    b1[nq][0] = as_bf(*(const u16x8*)&lds[r + sw0]);
    b1[nq][1] = as_bf(*(const u16x8*)&lds[r + sw1]);
  }
#pragma unroll
  for (int mq = 0; mq < 4; mq++) {
    const int r = bufA + aRow + 4096 + mq * 1024;
    a1[mq][0] = as_bf(*(const u16x8*)&lds[r + sw0]);
    a1[mq][1] = as_bf(*(const u16x8*)&lds[r + sw1]);
  }
  mm_f<0, 0>(acc, a0, b0);
  mm_f<0, 1>(acc, a0, b1);
  mm_f<1, 1>(acc, a1, b1);
  mm_f<1, 0>(acc, a1, b0);
}

__device__ __forceinline__ void stage_all(const u16* gA, const u16* gB,
                                          u16* ldst, int t) {
  const size_t ko = (size_t)t * 64;
  const int lb = (t & 1) * 16384;
#pragma unroll
  for (int U = 0; U < 4; U++)
    GLL16(gA + (size_t)(U * 64) * KPW + ko, ldst + lb + U * 4096);
#pragma unroll
  for (int U = 0; U < 4; U++)
    GLL16(gB + (size_t)(U * 64) * KPW + ko, ldst + 32768 + lb + U * 4096);
}

// MODE 4: merged projections. A = xmb [32768][640].
//   blocks 0..383:  x rows   x wt cols 0..1535  (q row-major / v transposed)
//   blocks 384..575: mem rows x wt cols 1536..2303 (k row-major)
// MODE 2: A = attn [16384][640], Bt = wpt [768][640]; f32 out + bias, guard n<584.
template <int MODE>
__global__ __launch_bounds__(512, 2) void gemm8_kernel(
    const u16* __restrict__ A, const u16* __restrict__ Bt,
    void* __restrict__ CoutV, void* __restrict__ CoutV2,
    const float* __restrict__ bias) {
  extern __shared__ u16 lds[];
  const int tid  = threadIdx.x;
  const int lane = tid & 63;
  const int q15  = lane & 15;
  const int quad = lane >> 4;
  const int wave = tid >> 6;
  const int wmi  = wave >> 2;     // 0..1
  const int wni  = wave & 3;      // 0..3

  // XCD-contiguous swizzle (grid % 8 == 0 for both modes)
  const int cpx = gridDim.x >> 3;
  const int bid = (blockIdx.x & 7) * cpx + (blockIdx.x >> 3);

  int m0, n0, npart;  // npart: 0=q 1=v 2=k (MODE4)
  if (MODE == 4) {
    if (bid < 384) {
      m0 = (bid / 6) * 256; int nt = bid % 6;
      n0 = nt * 256; npart = (nt >= 3) ? 1 : 0;
    } else {
      int b2 = bid - 384;
      m0 = NR + (b2 / 3) * 256; n0 = 1536 + (b2 % 3) * 256; npart = 2;
    }
  } else {
    m0 = (bid / 3) * 256; n0 = (bid % 3) * 256; npart = 0;
  }

  // staging geometry: thread t covers (row = t>>3, 16B chunk = t&7) of a 64-row unit;
  // source chunk pre-swizzled so that a swizzled ds_read finds linear data.
  const int tr   = tid >> 3;
  const int scol = ((tid & 7) ^ (tr & 7)) * 8;
  const u16* gA = &A[(size_t)(m0 + tr) * KPW + scol];
  const u16* gB = &Bt[(size_t)(n0 + tr) * KPW + scol];
  u16* ldst = &lds[tid * 8];

  // fragment-read swizzled 16B-slot offsets (row&7 == q15&7 for all frag rows)
  const int rb  = q15 & 7;
  const int sw0 = (quad ^ rb) * 8;
  const int sw1 = ((quad + 4) ^ rb) * 8;
  const int aRow = (wmi * 128 + q15) * 64;
  const int bRow = (wni * 64 + q15) * 64;

  f32x4 acc[8][4];
#pragma unroll
  for (int i = 0; i < 8; i++)
#pragma unroll
    for (int j = 0; j < 4; j++) acc[i][j] = (f32x4){0.f, 0.f, 0.f, 0.f};

  // prologue: T0 and T1 staged; wait T0 (8 newest = T1 stay in flight)
  stage_all(gA, gB, ldst, 0);
  stage_all(gA, gB, ldst, 1);
  VMW8(); BARRIER();

#pragma unroll 1
  for (int t = 0; t < KT64; ++t) {
    compute_tile(acc, lds, (t & 1) * 16384, aRow, bRow, sw0, sw1);
    if (t == KT64 - 1) break;
    BARRIER();                       // all waves done reading buf(t)
    if (t + 2 < KT64) {
      stage_all(gA, gB, ldst, t + 2);  // into buf(t), now free
      VMW8();                          // t+1's 8 loads (oldest) complete
    } else {
      VMW0();                          // last tile: drain
    }
    BARRIER();                       // t+1 visible to all waves
  }

  // epilogue: C row = m0 + wmi*128 + mf*16 + quad*4 + r ; col = n0 + wni*64 + nf*16 + q15
  const int rowb = m0 + wmi * 128 + quad * 4;
  const int colb = n0 + wni * 64 + q15;
  if (MODE == 4) {
    if (npart == 2) {          // k projection: mem rows, cols 1536.. -> k_buf
      u16* Cout = (u16*)CoutV2;
#pragma unroll
      for (int mf = 0; mf < 8; mf++)
#pragma unroll
        for (int nf = 0; nf < 4; nf++) {
          const int rk = rowb + mf * 16 - NR;
          const int ck = colb + nf * 16 - 1536;
#pragma unroll
          for (int r = 0; r < 4; r++)
            Cout[(size_t)(rk + r) * HD + ck] = f2bf(acc[mf][nf][r]);
        }
    } else if (npart == 0) {   // q projection, row-major
      u16* Cout = (u16*)CoutV;
#pragma unroll
      for (int mf = 0; mf < 8; mf++)
#pragma unroll
        for (int nf = 0; nf < 4; nf++) {
          const int row = rowb + mf * 16;
          const int col = colb + nf * 16;
#pragma unroll
          for (int r = 0; r < 4; r++)
            Cout[(size_t)(row + r) * HD + col] = f2bf(acc[mf][nf][r]);
        }
    } else {                   // v projection, transposed store
      u16* Cout = (u16*)CoutV;
#pragma unroll
      for (int mf = 0; mf < 8; mf++) {
        const int row = rowb + mf * 16;
        const int bb  = row >> 10;
        const int tl  = row & 1023;
#pragma unroll
        for (int nf = 0; nf < 4; nf++) {
          const int vn = colb + nf * 16 - HD;
          u16x4 pk;
#pragma unroll
          for (int r = 0; r < 4; r++) pk[r] = f2bf(acc[mf][nf][r]);
          *(u16x4*)&Cout[(size_t)(NR * HD) + ((size_t)(bb * HD + vn)) * TSEQ + tl] = pk;
        }
      }
    }
  } else {
    float* Cout = (float*)CoutV;
#pragma unroll
    for (int mf = 0; mf < 8; mf++)
#pragma unroll
      for (int nf = 0; nf < 4; nf++) {
        const int col = colb + nf * 16;
        if (col < CC) {
          const float bvv = bias[col];
          const int row = rowb + mf * 16;
#pragma unroll
          for (int r = 0; r < 4; r++)
            Cout[(size_t)(row + r) * CC + col] = acc[mf][nf][r] + bvv;
        }
      }
  }
}

// ---------------- flash attention (unchanged structure; KPW=640 pad) -------------
// q,k: [B,T,768] bf16 ; vt: [B,768,T] bf16 ; out attn: [16384][640] bf16 padded
__global__ __launch_bounds__(256, 3) void attn_kernel(
    const u16* __restrict__ qb, const u16* __restrict__ kb,
    const u16* __restrict__ vt, u16* __restrict__ attn) {
  __shared__ u16 smem[128 * 96 + 64 * 104 + 96 * 72];
  u16* Qs = smem;                       // [128][96]; later aliased by Pt
  u16* Ks = smem + 128 * 96;            // [64][104] pitch-padded
  u16* Vs = smem + 128 * 96 + 64 * 104; // [96][72]  pitch-padded
  u16* Pt = smem;                       // per-wave [32 q][pitch 88]

  const int tid  = threadIdx.x;
  const int lane = tid & 63;
  const int wave = tid >> 6;
  const int q15  = lane & 15;
  const int quad = lane >> 4;
  // XCD swizzle: bid%8 = XCD; all 8 t-tiles of one (b,h) on the same XCD
  const int bid  = blockIdx.x;
  const int loc  = bid >> 3;
  const int pair = (bid & 7) * 16 + (loc >> 3);
  const int b  = pair >> 3;
  const int h  = pair & 7;
  const int t0 = (loc & 7) * 128;
  const int wq0 = wave * 32;

  int krow[3], kc[3], vrow[3], vc[3];
#pragma unroll
  for (int p = 0; p < 3; p++) {
    int qk = tid + 256 * p;
    krow[p] = qk / 12; kc[p] = (qk % 12) * 8;
    int qv = tid + 256 * p;
    vrow[p] = qv / 8;  vc[p] = (qv % 8) * 8;
  }
  const u16* kbase = &kb[(size_t)(b * TSEQ) * HD + h * DP];
  const u16* vbase = &vt[(size_t)(b * HD + h * DP) * TSEQ];

  // stage Q tile [128][96]
  for (int q = tid; q < 128 * 12; q += 256) {
    int row = q / 12, c8 = (q % 12) * 8;
    *(u16x8*)&Qs[row * 96 + c8] =
        *(const u16x8*)&qb[(size_t)(b * TSEQ + t0 + row) * HD + h * DP + c8];
  }
  // zero pad cols 584..639 of this block's output rows
  if (tid < 128) {
    const u16x8 z = {0, 0, 0, 0, 0, 0, 0, 0};
    size_t base = (size_t)(b * TSEQ + t0 + tid) * KPW + CC;
#pragma unroll
    for (int c = 0; c < (KPW - CC) / 8; c++) *(u16x8*)&attn[base + c * 8] = z;
  }
  __syncthreads();

  bf16x8 aq[2][3];
#pragma unroll
  for (int n = 0; n < 2; n++)
#pragma unroll
    for (int kcx = 0; kcx < 3; kcx++)
      aq[n][kcx] = as_bf(*(const u16x8*)&Qs[(wq0 + n * 16 + q15) * 96 + kcx * 32 + quad * 8]);

  float lsum[2] = {0.f, 0.f};
  f32x4 oacc[2][6];
#pragma unroll
  for (int m = 0; m < 2; m++)
#pragma unroll
    for (int jd = 0; jd < 6; jd++) oacc[m][jd] = (f32x4){0.f, 0.f, 0.f, 0.f};

  u16* Ptw = &Pt[wave * 32 * PPITCH];

  u16x8 kreg[3], vreg[3];
#pragma unroll
  for (int p = 0; p < 3; p++) {
    kreg[p] = *(const u16x8*)&kbase[(size_t)krow[p] * HD + kc[p]];
    vreg[p] = *(const u16x8*)&vbase[(size_t)vrow[p] * TSEQ + vc[p]];
  }

  for (int si = 0; si < 16; ++si) {
#pragma unroll
    for (int p = 0; p < 3; p++) {
      *(u16x8*)&Ks[krow[p] * 104 + kc[p]] = kreg[p];
      *(u16x8*)&Vs[vrow[p] * 72 + vc[p]]  = vreg[p];
    }
    __syncthreads();

    if (si < 15) {
      const int s1 = (si + 1) * 64;
#pragma unroll
      for (int p = 0; p < 3; p++) {
        kreg[p] = *(const u16x8*)&kbase[(size_t)(s1 + krow[p]) * HD + kc[p]];
        vreg[p] = *(const u16x8*)&vbase[(size_t)vrow[p] * TSEQ + s1 + vc[p]];
      }
    }

    f32x4 st[4][2];
#pragma unroll
    for (int mt = 0; mt < 4; mt++)
#pragma unroll
      for (int n = 0; n < 2; n++) st[mt][n] = (f32x4){0.f, 0.f, 0.f, 0.f};
#pragma unroll
    for (int kcx = 0; kcx < 3; kcx++) {
      bf16x8 ak[4];
#pragma unroll
      for (int mt = 0; mt < 4; mt++)
        ak[mt] = as_bf(*(const u16x8*)&Ks[(mt * 16 + q15) * 104 + kcx * 32 + quad * 8]);
#pragma unroll
      for (int mt = 0; mt < 4; mt++)
#pragma unroll
        for (int n = 0; n < 2; n++)
          st[mt][n] = __builtin_amdgcn_mfma_f32_16x16x32_bf16(ak[mt], aq[n][kcx], st[mt][n], 0, 0, 0);
    }

#pragma unroll
    for (int mt = 0; mt < 4; mt++)
#pragma unroll
      for (int n = 0; n < 2; n++) {
        f32x4 pv;
#pragma unroll
        for (int r = 0; r < 4; r++) pv[r] = __builtin_amdgcn_exp2f(st[mt][n][r] * CEXP);
        lsum[n] += (pv[0] + pv[1]) + (pv[2] + pv[3]);
        u16x4 pk;
#pragma unroll
        for (int r = 0; r < 4; r++) pk[r] = f2bf(pv[r]);
        *(u16x4*)&Ptw[(n * 16 + q15) * PPITCH + mt * 16 + quad * 4] = pk;
      }

#pragma unroll
    for (int kcx = 0; kcx < 2; kcx++) {
      bf16x8 ap[2];
#pragma unroll
      for (int m = 0; m < 2; m++)
        ap[m] = as_bf(*(const u16x8*)&Ptw[(m * 16 + q15) * PPITCH + kcx * 32 + quad * 8]);
#pragma unroll
      for (int jd = 0; jd < 6; jd++) {
        bf16x8 bv = as_bf(*(const u16x8*)&Vs[(jd * 16 + q15) * 72 + kcx * 32 + quad * 8]);
#pragma unroll
        for (int m = 0; m < 2; m++)
          oacc[m][jd] = __builtin_amdgcn_mfma_f32_16x16x32_bf16(ap[m], bv, oacc[m][jd], 0, 0, 0);
      }
    }
    __syncthreads();
  }

  float lr[2];
#pragma unroll
  for (int n = 0; n < 2; n++) {
    float s = lsum[n];
    s += __shfl_xor(s, 16);
    s += __shfl_xor(s, 32);
    lr[n] = s;
  }

#pragma unroll
  for (int m = 0; m < 2; m++) {
#pragma unroll
    for (int r = 0; r < 4; r++) {
      const float inv = 1.f / __shfl(lr[m], quad * 4 + r);
      const int trow = t0 + wq0 + m * 16 + quad * 4 + r;
#pragma unroll
      for (int jd = 0; jd < 5; jd++) {
        const int d = jd * 16 + q15;
        if (d < DHD)
          attn[(size_t)(b * TSEQ + trow) * KPW + h * DHD + d] = f2bf(oacc[m][jd][r] * inv);
      }
    }
  }
}

// ---------------- launch ----------------

extern "C" void kernel_launch(void* const* d_in, const int* in_sizes, int n_in,
                              void* d_out, int out_size, void* d_ws, size_t ws_size,
                              hipStream_t stream) {
  const float* x   = (const float*)d_in[0];
  const float* mem = (const float*)d_in[1];
  const float* Wq  = (const float*)d_in[2];
  const float* Wk  = (const float*)d_in[3];
  const float* Wv  = (const float*)d_in[4];
  const float* Wp  = (const float*)d_in[5];
  const float* bp  = (const float*)d_in[6];
  float* out = (float*)d_out;

  char* ws = (char*)d_ws;
  const size_t SZ_XMB = (size_t)2 * NR * KPW * 2;  // 41,943,040
  const size_t SZ_WT  = (size_t)3 * HD * KPW * 2;  //  2,949,120 (q|v|k rows)
  const size_t SZ_WPT = (size_t)NP3 * KPW * 2;     //    983,040
  const size_t SZ_QB  = (size_t)NR * HD * 2;       // 25,165,824

  u16* xmb    = (u16*)(ws);            // [32768][640]; dead after projections
  u16* attn_o = (u16*)(ws);            // alias: [16384][640] padded
  u16* wt     = (u16*)(ws + SZ_XMB);
  u16* wp_t   = (u16*)(ws + SZ_XMB + SZ_WT);
  u16* q_buf  = (u16*)(ws + SZ_XMB + SZ_WT + SZ_WPT);       // q then vt contiguous
  u16* vt_buf = q_buf + (size_t)NR * HD;
  u16* k_buf  = (u16*)(ws + SZ_XMB + SZ_WT + SZ_WPT + 2 * SZ_QB);
  // total ws use: 41.9 + 2.9 + 1.0 + 75.5 MB ~= 121.4 MB

  (void)in_sizes; (void)n_in; (void)out_size; (void)ws_size;

  static bool s_attr = false;
  if (!s_attr) {
    (void)hipFuncSetAttribute((const void*)gemm8_kernel<4>,
                              hipFuncAttributeMaxDynamicSharedMemorySize, 131072);
    (void)hipFuncSetAttribute((const void*)gemm8_kernel<2>,
                              hipFuncAttributeMaxDynamicSharedMemorySize, 131072);
    s_attr = true;
  }

  // fused packs
  pack_all_kernel<<<PKA + PKB + PKC, 256, 0, stream>>>(x, mem, Wq, Wk, Wv, Wp,
                                                       xmb, wt, wp_t);

  // all three projections in ONE launch (x rows: q+v; mem rows: k)
  gemm8_kernel<4><<<576, 512, 131072, stream>>>(xmb, wt, q_buf, k_buf, nullptr);

  // attention (writes attn_o with zeroed pad, aliasing dead xmb)
  attn_kernel<<<BB * HH * (TSEQ / 128), 256, 0, stream>>>(q_buf, k_buf, vt_buf, attn_o);

  // output projection + bias -> f32 out (N padded to 768)
  gemm8_kernel<2><<<192, 512, 131072, stream>>>(attn_o, wp_t, out, nullptr, bp);
}

// Round 3
// 291.770 us; speedup vs baseline: 1.0132x; 1.0132x over previous
//
#include <hip/hip_runtime.h>
#include <hip/hip_bf16.h>

typedef unsigned short u16;
typedef __attribute__((ext_vector_type(4))) unsigned short u16x4;
typedef __attribute__((ext_vector_type(8))) unsigned short u16x8;
typedef __attribute__((ext_vector_type(8))) __bf16 bf16x8;
typedef __attribute__((ext_vector_type(4))) float f32x4;

#define BB 16
#define TSEQ 1024
#define CC 584          /* embed dim */
#define HH 8
#define DHD 73
#define NR (BB*TSEQ)    /* 16384 rows */
#define KPW 640         /* padded K: 10 x 64 -> 5 iters x 2 K-tiles */
#define DP 96           /* padded head dim */
#define HD (HH*DP)      /* 768 */
#define NP3 768         /* padded N for final proj (3 x 256 tiles) */
#define PPITCH 88
/* exp(s*584^-0.5) == exp2(s * CEXP); scores bounded -> no max subtraction */
#define CEXP 0.0596985934f

__device__ __forceinline__ u16 f2bf(float f) {
  __bf16 h = (__bf16)f;                 // native v_cvt, RNE
  return __builtin_bit_cast(u16, h);
}
__device__ __forceinline__ bf16x8 as_bf(u16x8 v) { return __builtin_bit_cast(bf16x8, v); }

/* async global->LDS, 16B/lane, LDS dst = wave-uniform base + lane*16 */
#define GLL16(g, l) __builtin_amdgcn_global_load_lds( \
    (const __attribute__((address_space(1))) void*)(g), \
    (__attribute__((address_space(3))) void*)(l), 16, 0, 0)

#define BARRIER() asm volatile("s_barrier" ::: "memory")
#define LGKM0()   asm volatile("s_waitcnt lgkmcnt(0)" ::: "memory")
#define VMW4()    asm volatile("s_waitcnt vmcnt(4)" ::: "memory")
#define VMW2()    asm volatile("s_waitcnt vmcnt(2)" ::: "memory")
#define VMW0()    asm volatile("s_waitcnt vmcnt(0)" ::: "memory")

// ---------------- fused pack kernel ----------------
#define PKA 10240
#define PKB 5760
#define PKC 1920
__global__ void pack_all_kernel(const float* __restrict__ x, const float* __restrict__ mem,
                                const float* __restrict__ Wq, const float* __restrict__ Wk,
                                const float* __restrict__ Wv, const float* __restrict__ Wp,
                                u16* __restrict__ xmb, u16* __restrict__ wt,
                                u16* __restrict__ wpt) {
  const int bidx = blockIdx.x;
  const int tid = threadIdx.x;
  if (bidx < PKA) {
    int idx = bidx * 256 + tid;
    int row = idx / (KPW / 8);
    int c8  = (idx % (KPW / 8)) * 8;
    u16x8 o = {0, 0, 0, 0, 0, 0, 0, 0};
    if (c8 < CC) {
      const float* src = (row < NR) ? &x[(size_t)row * CC + c8]
                                    : &mem[(size_t)(row - NR) * CC + c8];
      f32x4 a = *(const f32x4*)src;
      f32x4 b = *(const f32x4*)(src + 4);
#pragma unroll
      for (int t = 0; t < 4; t++) { o[t] = f2bf(a[t]); o[4 + t] = f2bf(b[t]); }
    }
    *(u16x8*)&xmb[(size_t)row * KPW + c8] = o;
  } else if (bidx < PKA + PKB) {
    int idx = (bidx - PKA) * 256 + tid;
    int w   = idx / (HD * KPW);
    int rem = idx % (HD * KPW);
    int n = rem / KPW;
    int k = rem % KPW;
    int h = n / DP, d = n % DP;
    u16 val = 0;
    if (d < DHD && k < CC) {
      const float* W = (w == 0) ? Wq : ((w == 1) ? Wv : Wk);  // order: q, v, k
      val = f2bf(W[((size_t)h * CC + k) * DHD + d]);
    }
    wt[idx] = val;
  } else {
    int idx = (bidx - PKA - PKB) * 256 + tid;
    int n = idx / KPW;
    int c = idx % KPW;
    u16 val = 0;
    if (n < CC && c < CC) val = f2bf(Wp[(size_t)c * CC + n]);
    wpt[idx] = val;
  }
}

// ---------------- 256x256 8-phase GEMM (m201 template port) ----------------
// 512 threads = 8 waves; wave rows = mh*128 + wmi*64 + [0,64), cols = nh*128 +
// wni*32 + [0,32) -> every phase (mh,nh) reads exactly one A block-half and one
// B block-half across ALL waves. LDS (128 KiB, 2 bufs): per buf A0|A1|B0|B1
// regions of 8192 u16 (128 rows x 64 K). Per phase: {ds_reads for this
// quadrant; stage ONE half-tile (2 gl_lds, 3 phases ahead); vmcnt(4); barrier;
// lgkmcnt(0); setprio(1); 16 MFMA; setprio(0); barrier}. A frags cached over
// nh, B0/B1 cached over mh -> 24 ds_read_b128 / K-tile / wave.
// Stage plan (iter i computes tiles t0=2i (buf0), t1=2i+1 (buf1)):
//   ph1:S(b1.A0,t1) ph2:S(b1.B0,t1) ph3:S(b1.B1,t1) ph4:S(b1.A1,t1)
//   ph5:S(b0.A0,t2) ph6:S(b0.B0,t2) ph7:S(b0.B1,t2) ph8:S(b0.A1,t2) [i<4]
// vmcnt(4) at phase p retires stage(p-2); its region is first read at p+1.
// Tail (i==4): ph5 vmcnt(2), ph6 vmcnt(0). Verified: readiness + clobber hold
// at every phase incl. iteration boundary and prologue.

template <int BUF, int MH>
__device__ __forceinline__ void rd_a(bf16x8 (&a)[4][2], const u16* lds, int arow,
                                     int sw0, int sw1) {
#pragma unroll
  for (int mq = 0; mq < 4; mq++) {
    const int r = BUF * 32768 + MH * 8192 + arow + mq * 1024;
    a[mq][0] = as_bf(*(const u16x8*)&lds[r + sw0]);
    a[mq][1] = as_bf(*(const u16x8*)&lds[r + sw1]);
  }
}
template <int BUF, int NH>
__device__ __forceinline__ void rd_b(bf16x8 (&b)[2][2], const u16* lds, int brow,
                                     int sw0, int sw1) {
#pragma unroll
  for (int nq = 0; nq < 2; nq++) {
    const int r = BUF * 32768 + 16384 + NH * 8192 + brow + nq * 1024;
    b[nq][0] = as_bf(*(const u16x8*)&lds[r + sw0]);
    b[nq][1] = as_bf(*(const u16x8*)&lds[r + sw1]);
  }
}
// RG: 0=A0, 1=A1, 2=B0, 3=B1 ; half-tile = 128 rows x 64 K = 2 loads/thread
template <int BUF, int RG>
__device__ __forceinline__ void stg(const u16* gA, const u16* gB, u16* ldst, int t) {
  const u16* src = (RG < 2) ? gA : gB;
  const int rrow = (RG & 1) * 128;
  const int loff = BUF * 32768 + (RG >> 1) * 16384 + (RG & 1) * 8192;
  GLL16(src + (size_t)rrow * KPW + (size_t)t * 64, ldst + loff);
  GLL16(src + (size_t)(rrow + 64) * KPW + (size_t)t * 64, ldst + loff + 4096);
}
template <int MH, int NH>
__device__ __forceinline__ void mmq(f32x4 (&acc)[8][4], const bf16x8 (&a)[4][2],
                                    const bf16x8 (&b)[2][2]) {
  __builtin_amdgcn_s_setprio(1);
#pragma unroll
  for (int mq = 0; mq < 4; mq++)
#pragma unroll
    for (int nq = 0; nq < 2; nq++) {
      f32x4 c = acc[MH * 4 + mq][NH * 2 + nq];
      c = __builtin_amdgcn_mfma_f32_16x16x32_bf16(a[mq][0], b[nq][0], c, 0, 0, 0);
      c = __builtin_amdgcn_mfma_f32_16x16x32_bf16(a[mq][1], b[nq][1], c, 0, 0, 0);
      acc[MH * 4 + mq][NH * 2 + nq] = c;
    }
  __builtin_amdgcn_s_setprio(0);
}

// MODE 4: merged projections. MODE 2: final proj + bias -> f32.
template <int MODE>
__global__ __launch_bounds__(512, 2) void gemm8_kernel(
    const u16* __restrict__ A, const u16* __restrict__ Bt,
    void* __restrict__ CoutV, void* __restrict__ CoutV2,
    const float* __restrict__ bias) {
  extern __shared__ u16 lds[];
  const int tid  = threadIdx.x;
  const int lane = tid & 63;
  const int q15  = lane & 15;
  const int quad = lane >> 4;
  const int wave = tid >> 6;
  const int wmi  = wave >> 2;     // 0..1
  const int wni  = wave & 3;      // 0..3

  // XCD-contiguous swizzle (grid % 8 == 0 for both modes)
  const int cpx = gridDim.x >> 3;
  const int bid = (blockIdx.x & 7) * cpx + (blockIdx.x >> 3);

  int m0, n0, npart;  // npart: 0=q 1=v 2=k (MODE4)
  if (MODE == 4) {
    if (bid < 384) {
      m0 = (bid / 6) * 256; int nt = bid % 6;
      n0 = nt * 256; npart = (nt >= 3) ? 1 : 0;
    } else {
      int b2 = bid - 384;
      m0 = NR + (b2 / 3) * 256; n0 = 1536 + (b2 % 3) * 256; npart = 2;
    }
  } else {
    m0 = (bid / 3) * 256; n0 = (bid % 3) * 256; npart = 0;
  }

  // staging geometry: thread t covers (row = t>>3, chunk = t&7) of a 64-row unit;
  // source chunk pre-swizzled so swizzled ds_read finds linear data (T2 rule 21).
  const int tr   = tid >> 3;
  const int scol = ((tid & 7) ^ (tr & 7)) * 8;
  const u16* gA = &A[(size_t)(m0 + tr) * KPW + scol];
  const u16* gB = &Bt[(size_t)(n0 + tr) * KPW + scol];
  u16* ldst = &lds[tid * 8];

  // fragment-read swizzled 16B-slot offsets (frag row & 7 == q15 & 7)
  const int rb  = q15 & 7;
  const int sw0 = (quad ^ rb) * 8;
  const int sw1 = ((quad + 4) ^ rb) * 8;
  const int arow = (wmi * 64 + q15) * 64;
  const int brow = (wni * 32 + q15) * 64;

  f32x4 acc[8][4];
#pragma unroll
  for (int i = 0; i < 8; i++)
#pragma unroll
    for (int j = 0; j < 4; j++) acc[i][j] = (f32x4){0.f, 0.f, 0.f, 0.f};
  bf16x8 a[4][2], b0[2][2], b1[2][2];

  // prologue: tile 0 -> buf0, order A0,B0,B1,A1; vmcnt(4) -> A0,B0 landed
  stg<0, 0>(gA, gB, ldst, 0);
  stg<0, 2>(gA, gB, ldst, 0);
  stg<0, 3>(gA, gB, ldst, 0);
  stg<0, 1>(gA, gB, ldst, 0);
  VMW4(); BARRIER();

#pragma unroll 1
  for (int i = 0; i < 5; ++i) {
    const int t1 = 2 * i + 1;
    const int t2 = 2 * i + 2;
    const bool st = (i < 4);
    // ph1: (0,0) buf0
    rd_a<0, 0>(a, lds, arow, sw0, sw1);
    rd_b<0, 0>(b0, lds, brow, sw0, sw1);
    stg<1, 0>(gA, gB, ldst, t1);
    VMW4(); BARRIER(); LGKM0();
    mmq<0, 0>(acc, a, b0);
    BARRIER();
    // ph2: (0,1) buf0 (a cached)
    rd_b<0, 1>(b1, lds, brow, sw0, sw1);
    stg<1, 2>(gA, gB, ldst, t1);
    VMW4(); BARRIER(); LGKM0();
    mmq<0, 1>(acc, a, b1);
    BARRIER();
    // ph3: (1,0) buf0 (b0 cached)
    rd_a<0, 1>(a, lds, arow, sw0, sw1);
    stg<1, 3>(gA, gB, ldst, t1);
    VMW4(); BARRIER(); LGKM0();
    mmq<1, 0>(acc, a, b0);
    BARRIER();
    // ph4: (1,1) buf0 (a, b1 cached)
    stg<1, 1>(gA, gB, ldst, t1);
    VMW4(); BARRIER();
    mmq<1, 1>(acc, a, b1);
    BARRIER();
    // ph5: (0,0) buf1
    rd_a<1, 0>(a, lds, arow, sw0, sw1);
    rd_b<1, 0>(b0, lds, brow, sw0, sw1);
    if (st) { stg<0, 0>(gA, gB, ldst, t2); VMW4(); } else { VMW2(); }
    BARRIER(); LGKM0();
    mmq<0, 0>(acc, a, b0);
    BARRIER();
    // ph6: (0,1) buf1
    rd_b<1, 1>(b1, lds, brow, sw0, sw1);
    if (st) { stg<0, 2>(gA, gB, ldst, t2); VMW4(); } else { VMW0(); }
    BARRIER(); LGKM0();
    mmq<0, 1>(acc, a, b1);
    BARRIER();
    // ph7: (1,0) buf1
    rd_a<1, 1>(a, lds, arow, sw0, sw1);
    if (st) { stg<0, 3>(gA, gB, ldst, t2); VMW4(); }
    BARRIER(); LGKM0();
    mmq<1, 0>(acc, a, b0);
    BARRIER();
    // ph8: (1,1) buf1
    if (st) { stg<0, 1>(gA, gB, ldst, t2); VMW4(); }
    BARRIER();
    mmq<1, 1>(acc, a, b1);
    BARRIER();
  }

  // epilogue: row = m0 + mh*128 + wmi*64 + mq*16 + quad*4 + r
  //           col = n0 + nh*128 + wni*32 + nq*16 + q15
  const int rowb = m0 + wmi * 64 + quad * 4;
  const int colb = n0 + wni * 32 + q15;
#pragma unroll
  for (int mh = 0; mh < 2; mh++)
#pragma unroll
    for (int mq = 0; mq < 4; mq++)
#pragma unroll
      for (int nh = 0; nh < 2; nh++)
#pragma unroll
        for (int nq = 0; nq < 2; nq++) {
          const f32x4 av = acc[mh * 4 + mq][nh * 2 + nq];
          const int row = rowb + mh * 128 + mq * 16;
          const int col = colb + nh * 128 + nq * 16;
          if (MODE == 4) {
            if (npart == 2) {          // k projection -> k_buf
              u16* Cout = (u16*)CoutV2;
              const int rk = row - NR;
              const int ck = col - 1536;
#pragma unroll
              for (int r = 0; r < 4; r++)
                Cout[(size_t)(rk + r) * HD + ck] = f2bf(av[r]);
            } else if (npart == 0) {   // q projection, row-major
              u16* Cout = (u16*)CoutV;
#pragma unroll
              for (int r = 0; r < 4; r++)
                Cout[(size_t)(row + r) * HD + col] = f2bf(av[r]);
            } else {                   // v projection, transposed store
              u16* Cout = (u16*)CoutV;
              const int vn = col - HD;
              const int bb = row >> 10;
              const int tl = row & 1023;
              u16x4 pk;
#pragma unroll
              for (int r = 0; r < 4; r++) pk[r] = f2bf(av[r]);
              *(u16x4*)&Cout[(size_t)(NR * HD) + ((size_t)(bb * HD + vn)) * TSEQ + tl] = pk;
            }
          } else {
            if (col < CC) {
              float* Cout = (float*)CoutV;
              const float bvv = bias[col];
#pragma unroll
              for (int r = 0; r < 4; r++)
                Cout[(size_t)(row + r) * CC + col] = av[r] + bvv;
            }
          }
        }
}

// ---------------- flash attention (unchanged; KPW=640 pad) -------------
__global__ __launch_bounds__(256, 3) void attn_kernel(
    const u16* __restrict__ qb, const u16* __restrict__ kb,
    const u16* __restrict__ vt, u16* __restrict__ attn) {
  __shared__ u16 smem[128 * 96 + 64 * 104 + 96 * 72];
  u16* Qs = smem;                       // [128][96]; later aliased by Pt
  u16* Ks = smem + 128 * 96;            // [64][104] pitch-padded
  u16* Vs = smem + 128 * 96 + 64 * 104; // [96][72]  pitch-padded
  u16* Pt = smem;                       // per-wave [32 q][pitch 88]

  const int tid  = threadIdx.x;
  const int lane = tid & 63;
  const int wave = tid >> 6;
  const int q15  = lane & 15;
  const int quad = lane >> 4;
  const int bid  = blockIdx.x;
  const int loc  = bid >> 3;
  const int pair = (bid & 7) * 16 + (loc >> 3);
  const int b  = pair >> 3;
  const int h  = pair & 7;
  const int t0 = (loc & 7) * 128;
  const int wq0 = wave * 32;

  int krow[3], kc[3], vrow[3], vc[3];
#pragma unroll
  for (int p = 0; p < 3; p++) {
    int qk = tid + 256 * p;
    krow[p] = qk / 12; kc[p] = (qk % 12) * 8;
    int qv = tid + 256 * p;
    vrow[p] = qv / 8;  vc[p] = (qv % 8) * 8;
  }
  const u16* kbase = &kb[(size_t)(b * TSEQ) * HD + h * DP];
  const u16* vbase = &vt[(size_t)(b * HD + h * DP) * TSEQ];

  for (int q = tid; q < 128 * 12; q += 256) {
    int row = q / 12, c8 = (q % 12) * 8;
    *(u16x8*)&Qs[row * 96 + c8] =
        *(const u16x8*)&qb[(size_t)(b * TSEQ + t0 + row) * HD + h * DP + c8];
  }
  if (tid < 128) {
    const u16x8 z = {0, 0, 0, 0, 0, 0, 0, 0};
    size_t base = (size_t)(b * TSEQ + t0 + tid) * KPW + CC;
#pragma unroll
    for (int c = 0; c < (KPW - CC) / 8; c++) *(u16x8*)&attn[base + c * 8] = z;
  }
  __syncthreads();

  bf16x8 aq[2][3];
#pragma unroll
  for (int n = 0; n < 2; n++)
#pragma unroll
    for (int kcx = 0; kcx < 3; kcx++)
      aq[n][kcx] = as_bf(*(const u16x8*)&Qs[(wq0 + n * 16 + q15) * 96 + kcx * 32 + quad * 8]);

  float lsum[2] = {0.f, 0.f};
  f32x4 oacc[2][6];
#pragma unroll
  for (int m = 0; m < 2; m++)
#pragma unroll
    for (int jd = 0; jd < 6; jd++) oacc[m][jd] = (f32x4){0.f, 0.f, 0.f, 0.f};

  u16* Ptw = &Pt[wave * 32 * PPITCH];

  u16x8 kreg[3], vreg[3];
#pragma unroll
  for (int p = 0; p < 3; p++) {
    kreg[p] = *(const u16x8*)&kbase[(size_t)krow[p] * HD + kc[p]];
    vreg[p] = *(const u16x8*)&vbase[(size_t)vrow[p] * TSEQ + vc[p]];
  }

  for (int si = 0; si < 16; ++si) {
#pragma unroll
    for (int p = 0; p < 3; p++) {
      *(u16x8*)&Ks[krow[p] * 104 + kc[p]] = kreg[p];
      *(u16x8*)&Vs[vrow[p] * 72 + vc[p]]  = vreg[p];
    }
    __syncthreads();

    if (si < 15) {
      const int s1 = (si + 1) * 64;
#pragma unroll
      for (int p = 0; p < 3; p++) {
        kreg[p] = *(const u16x8*)&kbase[(size_t)(s1 + krow[p]) * HD + kc[p]];
        vreg[p] = *(const u16x8*)&vbase[(size_t)vrow[p] * TSEQ + s1 + vc[p]];
      }
    }

    f32x4 st[4][2];
#pragma unroll
    for (int mt = 0; mt < 4; mt++)
#pragma unroll
      for (int n = 0; n < 2; n++) st[mt][n] = (f32x4){0.f, 0.f, 0.f, 0.f};
#pragma unroll
    for (int kcx = 0; kcx < 3; kcx++) {
      bf16x8 ak[4];
#pragma unroll
      for (int mt = 0; mt < 4; mt++)
        ak[mt] = as_bf(*(const u16x8*)&Ks[(mt * 16 + q15) * 104 + kcx * 32 + quad * 8]);
#pragma unroll
      for (int mt = 0; mt < 4; mt++)
#pragma unroll
        for (int n = 0; n < 2; n++)
          st[mt][n] = __builtin_amdgcn_mfma_f32_16x16x32_bf16(ak[mt], aq[n][kcx], st[mt][n], 0, 0, 0);
    }

#pragma unroll
    for (int mt = 0; mt < 4; mt++)
#pragma unroll
      for (int n = 0; n < 2; n++) {
        f32x4 pv;
#pragma unroll
        for (int r = 0; r < 4; r++) pv[r] = __builtin_amdgcn_exp2f(st[mt][n][r] * CEXP);
        lsum[n] += (pv[0] + pv[1]) + (pv[2] + pv[3]);
        u16x4 pk;
#pragma unroll
        for (int r = 0; r < 4; r++) pk[r] = f2bf(pv[r]);
        *(u16x4*)&Ptw[(n * 16 + q15) * PPITCH + mt * 16 + quad * 4] = pk;
      }

#pragma unroll
    for (int kcx = 0; kcx < 2; kcx++) {
      bf16x8 ap[2];
#pragma unroll
      for (int m = 0; m < 2; m++)
        ap[m] = as_bf(*(const u16x8*)&Ptw[(m * 16 + q15) * PPITCH + kcx * 32 + quad * 8]);
#pragma unroll
      for (int jd = 0; jd < 6; jd++) {
        bf16x8 bv = as_bf(*(const u16x8*)&Vs[(jd * 16 + q15) * 72 + kcx * 32 + quad * 8]);
#pragma unroll
        for (int m = 0; m < 2; m++)
          oacc[m][jd] = __builtin_amdgcn_mfma_f32_16x16x32_bf16(ap[m], bv, oacc[m][jd], 0, 0, 0);
      }
    }
    __syncthreads();
  }

  float lr[2];
#pragma unroll
  for (int n = 0; n < 2; n++) {
    float s = lsum[n];
    s += __shfl_xor(s, 16);
    s += __shfl_xor(s, 32);
    lr[n] = s;
  }

#pragma unroll
  for (int m = 0; m < 2; m++) {
#pragma unroll
    for (int r = 0; r < 4; r++) {
      const float inv = 1.f / __shfl(lr[m], quad * 4 + r);
      const int trow = t0 + wq0 + m * 16 + quad * 4 + r;
#pragma unroll
      for (int jd = 0; jd < 5; jd++) {
        const int d = jd * 16 + q15;
        if (d < DHD)
          attn[(size_t)(b * TSEQ + trow) * KPW + h * DHD + d] = f2bf(oacc[m][jd][r] * inv);
      }
    }
  }
}

// ---------------- launch ----------------

extern "C" void kernel_launch(void* const* d_in, const int* in_sizes, int n_in,
                              void* d_out, int out_size, void* d_ws, size_t ws_size,
                              hipStream_t stream) {
  const float* x   = (const float*)d_in[0];
  const float* mem = (const float*)d_in[1];
  const float* Wq  = (const float*)d_in[2];
  const float* Wk  = (const float*)d_in[3];
  const float* Wv  = (const float*)d_in[4];
  const float* Wp  = (const float*)d_in[5];
  const float* bp  = (const float*)d_in[6];
  float* out = (float*)d_out;

  char* ws = (char*)d_ws;
  const size_t SZ_XMB = (size_t)2 * NR * KPW * 2;  // 41,943,040
  const size_t SZ_WT  = (size_t)3 * HD * KPW * 2;  //  2,949,120 (q|v|k rows)
  const size_t SZ_WPT = (size_t)NP3 * KPW * 2;     //    983,040
  const size_t SZ_QB  = (size_t)NR * HD * 2;       // 25,165,824

  u16* xmb    = (u16*)(ws);            // [32768][640]; dead after projections
  u16* attn_o = (u16*)(ws);            // alias: [16384][640] padded
  u16* wt     = (u16*)(ws + SZ_XMB);
  u16* wp_t   = (u16*)(ws + SZ_XMB + SZ_WT);
  u16* q_buf  = (u16*)(ws + SZ_XMB + SZ_WT + SZ_WPT);       // q then vt contiguous
  u16* vt_buf = q_buf + (size_t)NR * HD;
  u16* k_buf  = (u16*)(ws + SZ_XMB + SZ_WT + SZ_WPT + 2 * SZ_QB);
  // total ws use: 41.9 + 2.9 + 1.0 + 75.5 MB ~= 121.4 MB

  (void)in_sizes; (void)n_in; (void)out_size; (void)ws_size;

  static bool s_attr = false;
  if (!s_attr) {
    (void)hipFuncSetAttribute((const void*)gemm8_kernel<4>,
                              hipFuncAttributeMaxDynamicSharedMemorySize, 131072);
    (void)hipFuncSetAttribute((const void*)gemm8_kernel<2>,
                              hipFuncAttributeMaxDynamicSharedMemorySize, 131072);
    s_attr = true;
  }

  // fused packs
  pack_all_kernel<<<PKA + PKB + PKC, 256, 0, stream>>>(x, mem, Wq, Wk, Wv, Wp,
                                                       xmb, wt, wp_t);

  // all three projections in ONE launch (x rows: q+v; mem rows: k)
  gemm8_kernel<4><<<576, 512, 131072, stream>>>(xmb, wt, q_buf, k_buf, nullptr);

  // attention (writes attn_o with zeroed pad, aliasing dead xmb)
  attn_kernel<<<BB * HH * (TSEQ / 128), 256, 0, stream>>>(q_buf, k_buf, vt_buf, attn_o);

  // output projection + bias -> f32 out (N padded to 768)
  gemm8_kernel<2><<<192, 512, 131072, stream>>>(attn_o, wp_t, out, nullptr, bp);
}